// Round 5
// baseline (380.133 us; speedup 1.0000x reference)
//
#include <hip/hip_runtime.h>
#include <math.h>

// Problem constants
#define BB 512
#define SS 128
#define VV 1024
#define NROWS (BB * SS)   // 65536
#define PAD_IDX 0

// Workspace layout (bytes)
#define OFF_CE   0            // float[NROWS]
#define OFF_PRED 262144       // int[NROWS]
#define OFF_PART 524288       // float part[10][512]  (SoA per-batch partials)
#define NPART 10

// ---------------------------------------------------------------------------
// Kernel 1: per-(b,s) row of V=1024 logits -> ce (smoothed, pad-masked), argmax.
// ILP-2: each wave owns TWO adjacent rows with fully interleaved independent
// chains (halves per-wave memory-idle time; cross-lane ops dual-schedule).
// 8192 blocks x 4 waves = 32768 waves: TLP still fully oversubscribed.
__global__ __launch_bounds__(256) void row_kernel(
    const float* __restrict__ logits, const int* __restrict__ tgt,
    float* __restrict__ ce, int* __restrict__ pred)
{
    const int lane = threadIdx.x & 63;
    const int wid  = blockIdx.x * 4 + (threadIdx.x >> 6);
    const int rowA = wid * 2;
    const int rowB = rowA + 1;
    const float4* baseA = reinterpret_cast<const float4*>(logits + (size_t)rowA * VV);
    const float4* baseB = reinterpret_cast<const float4*>(logits + (size_t)rowB * VV);

    // 16 floats/lane per row as 4x float4; element index = j*256 + lane*4 + k
    float4 va[4], vb[4];
#pragma unroll
    for (int j = 0; j < 4; ++j) { va[j] = baseA[j * 64 + lane]; vb[j] = baseB[j * 64 + lane]; }
    const int2 tt = *reinterpret_cast<const int2*>(tgt + rowA);
    const int ta = tt.x, tb = tt.y;

    // ---- pass 1: row max (pure fmax trees, interleaved)
    float ma = -INFINITY, mb = -INFINITY;
#pragma unroll
    for (int j = 0; j < 4; ++j) {
        ma = fmaxf(ma, fmaxf(fmaxf(va[j].x, va[j].y), fmaxf(va[j].z, va[j].w)));
        mb = fmaxf(mb, fmaxf(fmaxf(vb[j].x, vb[j].y), fmaxf(vb[j].z, vb[j].w)));
    }
#pragma unroll
    for (int off = 32; off > 0; off >>= 1) {
        ma = fmaxf(ma, __shfl_xor(ma, off, 64));
        mb = fmaxf(mb, __shfl_xor(mb, off, 64));
    }

    // ---- pass 2: sum exp(x-m), sum x, first-index argmax via equality
    float seA = 0.0f, sxA = 0.0f, seB = 0.0f, sxB = 0.0f;
    int amA = 0x7fffffff, amB = 0x7fffffff;
#pragma unroll
    for (int j = 0; j < 4; ++j) {
        float xsA[4] = {va[j].x, va[j].y, va[j].z, va[j].w};
        float xsB[4] = {vb[j].x, vb[j].y, vb[j].z, vb[j].w};
#pragma unroll
        for (int k = 0; k < 4; ++k) {
            const int idx = j * 256 + lane * 4 + k;
            float xA = xsA[k], xB = xsB[k];
            sxA += xA;                sxB += xB;
            seA += __expf(xA - ma);   seB += __expf(xB - mb);
            if (xA == ma) amA = min(amA, idx);
            if (xB == mb) amB = min(amB, idx);
        }
    }

    // x[target] via ONE shuffle each: element idx = j*256 + lane*4 + k
    const int jA = ta >> 8, lA = (ta >> 2) & 63, kA = ta & 3;
    float4 vjA = (jA == 0) ? va[0] : (jA == 1) ? va[1] : (jA == 2) ? va[2] : va[3];
    float xcA  = (kA == 0) ? vjA.x : (kA == 1) ? vjA.y : (kA == 2) ? vjA.z : vjA.w;
    const int jB = tb >> 8, lB = (tb >> 2) & 63, kB = tb & 3;
    float4 vjB = (jB == 0) ? vb[0] : (jB == 1) ? vb[1] : (jB == 2) ? vb[2] : vb[3];
    float xcB  = (kB == 0) ? vjB.x : (kB == 1) ? vjB.y : (kB == 2) ? vjB.z : vjB.w;
    float xtA  = __shfl(xcA, lA, 64);
    float xtB  = __shfl(xcB, lB, 64);

#pragma unroll
    for (int off = 32; off > 0; off >>= 1) {
        seA += __shfl_xor(seA, off, 64);   seB += __shfl_xor(seB, off, 64);
        sxA += __shfl_xor(sxA, off, 64);   sxB += __shfl_xor(sxB, off, 64);
        amA  = min(amA, __shfl_xor(amA, off, 64));
        amB  = min(amB, __shfl_xor(amB, off, 64));
    }

    if (lane == 0) {
        float lseA    = ma + __logf(seA);
        float lseB    = mb + __logf(seB);
        float ceA = 0.9f * (lseA - xtA) + 0.1f * (lseA - sxA * (1.0f / (float)VV));
        float ceB = 0.9f * (lseB - xtB) + 0.1f * (lseB - sxB * (1.0f / (float)VV));
        ce[rowA]   = (ta != PAD_IDX) ? ceA : 0.0f;
        ce[rowB]   = (tb != PAD_IDX) ? ceB : 0.0f;
        pred[rowA] = amA;
        pred[rowB] = amB;
    }
}

// ---------------------------------------------------------------------------
// Kernel 2: per-batch-row stats -> SoA partials (no atomics, no contention).
// part[k][b]: 0=sum cw, 1=sum w, 2=|plen-L|, 3=bi, 4=tri, 5=correct, 6=L,
//             7=end_ok, 8=len_eq, 9=front>0
__global__ __launch_bounds__(128) void batch_kernel(
    const int* __restrict__ tgt, const float* __restrict__ ce,
    const int* __restrict__ pred, float* __restrict__ part)
{
    const int b = blockIdx.x;
    const int s = threadIdx.x;
    const int wave = s >> 6, lane = s & 63;

    __shared__ int sh_t[SS], sh_p[SS];
    __shared__ int sL[2], sPL[2], sCor[2], sFront[2];
    __shared__ float sRW[2], sRCW[2];
    __shared__ int sRBi[2], sRTri[2];

    const int   t = tgt[b * SS + s];
    const int   p = pred[b * SS + s];
    const float c = ce[b * SS + s];
    sh_t[s] = t; sh_p[s] = p;

    unsigned long long bal;
    bal = __ballot(t != PAD_IDX);               if (!lane) sL[wave]     = __popcll(bal);
    bal = __ballot(p != PAD_IDX);               if (!lane) sPL[wave]    = __popcll(bal);
    bal = __ballot(p == t && t != PAD_IDX);     if (!lane) sCor[wave]   = __popcll(bal);
    bal = __ballot(t != PAD_IDX && s < SS - 2); if (!lane) sFront[wave] = __popcll(bal);
    __syncthreads();

    const int L    = sL[0] + sL[1];
    const int plen = sPL[0] + sPL[1];

    // position weights (pos == s)
    float Lf = fmaxf((float)L, 1.0f);
    float w  = (s < L) ? 1.0f + ((float)s / Lf) * 0.5f : 1.0f;
    if (s == L - 3 && L >= 3) w = 1.8f;
    if (s == L - 2 && L >= 2) w = 2.4f;
    if (s == L - 1 && L >= 1) w = 3.0f;
    float cw = c * w;

    // bigram / trigram (exact integer terms)
    int bi = 0, tri = 0;
    if (s < SS - 1) {
        int pe = (p == sh_p[s + 1]);
        int te = (t == sh_t[s + 1]);
        int sm = (p == t);
        bi = pe + te - 2 * (pe & te & sm);
        if (s < SS - 2) {
            int pe3 = pe & (sh_p[s + 1] == sh_p[s + 2]);
            int te3 = te & (sh_t[s + 1] == sh_t[s + 2]);
            tri = pe3 + te3 - 2 * (pe3 & te3 & sm);
        }
    }

    float rw = w, rcw = cw; int rbi = bi, rtri = tri;
#pragma unroll
    for (int off = 32; off > 0; off >>= 1) {
        rw   += __shfl_xor(rw,   off, 64);
        rcw  += __shfl_xor(rcw,  off, 64);
        rbi  += __shfl_xor(rbi,  off, 64);
        rtri += __shfl_xor(rtri, off, 64);
    }
    if (!lane) { sRW[wave] = rw; sRCW[wave] = rcw; sRBi[wave] = rbi; sRTri[wave] = rtri; }
    __syncthreads();

    if (s == 0) {
        float sumw  = sRW[0] + sRW[1];
        float sumcw = sRCW[0] + sRCW[1];
        int bis   = sRBi[0]  + sRBi[1];
        int tris  = sRTri[0] + sRTri[1];
        int cor   = sCor[0]  + sCor[1];
        int front = sFront[0] + sFront[1];

        int end_idx = L - 1; if (end_idx < 0) end_idx = 0; if (end_idx > SS - 1) end_idx = SS - 1;
        int eok = (L > 0) && (sh_p[end_idx] == sh_t[end_idx]);
        int d = plen - L; if (d < 0) d = -d;

        // All magnitudes < 2^24: exact in f32.
        part[0 * BB + b] = sumcw;
        part[1 * BB + b] = sumw;
        part[2 * BB + b] = (float)d;
        part[3 * BB + b] = (float)bis;
        part[4 * BB + b] = (float)tris;
        part[5 * BB + b] = (float)cor;
        part[6 * BB + b] = (float)L;
        part[7 * BB + b] = (float)eok;
        part[8 * BB + b] = (L == plen) ? 1.0f : 0.0f;
        part[9 * BB + b] = (front > 0) ? 1.0f : 0.0f;
    }
}

// ---------------------------------------------------------------------------
// Kernel 3: reduce 512 partial records -> 4 output scalars. 1 block, 512 thr.
__global__ __launch_bounds__(512) void finalize(
    const float* __restrict__ part, float* __restrict__ out)
{
    const int t = threadIdx.x;          // 0..511, one per batch row
    const int wave = t >> 6, lane = t & 63;

    float v[NPART];
#pragma unroll
    for (int k = 0; k < NPART; ++k) v[k] = part[k * BB + t];   // coalesced

#pragma unroll
    for (int off = 32; off > 0; off >>= 1)
#pragma unroll
        for (int k = 0; k < NPART; ++k) v[k] += __shfl_xor(v[k], off, 64);

    __shared__ float sh[NPART][8];
    if (!lane)
#pragma unroll
        for (int k = 0; k < NPART; ++k) sh[k][wave] = v[k];
    __syncthreads();

    if (t == 0) {
        float s[NPART];
#pragma unroll
        for (int k = 0; k < NPART; ++k) {
            s[k] = 0.0f;
            for (int wv = 0; wv < 8; ++wv) s[k] += sh[k][wv];
        }
        float weighted = s[0] / s[1];
        float lp   = 0.1f * s[2] / (float)BB;
        float bif  = s[3] / ((float)BB * (float)(SS - 1) * (float)VV);
        float trif = s[4] / ((float)BB * (float)(SS - 2) * (float)VV);
        float cng  = bif + (s[9] > 0.0f ? trif : 0.0f);
        out[0] = weighted + lp + 0.2f * cng;                   // total_loss
        out[1] = s[6] > 0.0f ? s[5] / s[6] : 0.0f;             // char_acc
        out[2] = s[7] / (float)BB;                             // end_char_acc
        out[3] = s[8] / (float)BB;                             // length_acc
    }
}

// ---------------------------------------------------------------------------
extern "C" void kernel_launch(void* const* d_in, const int* in_sizes, int n_in,
                              void* d_out, int out_size, void* d_ws, size_t ws_size,
                              hipStream_t stream)
{
    const float* logits = (const float*)d_in[0];
    const int*   tgt    = (const int*)d_in[1];
    float* out = (float*)d_out;

    char* ws = (char*)d_ws;
    float* ce   = (float*)(ws + OFF_CE);
    int*   pred = (int*)  (ws + OFF_PRED);
    float* part = (float*)(ws + OFF_PART);

    row_kernel<<<NROWS / 8, 256, 0, stream>>>(logits, tgt, ce, pred);
    batch_kernel<<<BB, SS, 0, stream>>>(tgt, ce, pred, part);
    finalize<<<1, 512, 0, stream>>>(part, out);
}

// Round 6
// 363.221 us; speedup vs baseline: 1.0466x; 1.0466x over previous
//
#include <hip/hip_runtime.h>
#include <math.h>

// Problem constants
#define BB 512
#define SS 128
#define VV 1024
#define NROWS (BB * SS)   // 65536
#define PAD_IDX 0

// Workspace layout (bytes)
#define OFF_CE   0            // float[NROWS]
#define OFF_PRED 262144       // int[NROWS]
#define OFF_PART 524288       // float part[10][512]  (SoA per-batch partials)
#define NPART 10

// ---------------------------------------------------------------------------
// Kernel 1: per-(b,s) row of V=1024 logits -> ce (smoothed, pad-masked), argmax.
// One wave (64 lanes) per row, 4 waves/block: maximal TLP. Best measured shape
// (R4: 370 us). R2 persistent-prefetch and R5 ILP-2 variants both regressed
// or were neutral -> kernel is BW-bound; keep it simple and oversubscribed.
__global__ __launch_bounds__(256) void row_kernel(
    const float* __restrict__ logits, const int* __restrict__ tgt,
    float* __restrict__ ce, int* __restrict__ pred)
{
    const int lane = threadIdx.x & 63;
    const int row  = blockIdx.x * 4 + (threadIdx.x >> 6);
    const float* base = logits + (size_t)row * VV;

    // 16 floats/lane as 4x float4; element index = j*256 + lane*4 + k
    float4 v[4];
#pragma unroll
    for (int j = 0; j < 4; ++j)
        v[j] = reinterpret_cast<const float4*>(base)[j * 64 + lane];
    const int t = tgt[row];

    // ---- pass 1: row max (pure fmax tree)
    float m = -INFINITY;
#pragma unroll
    for (int j = 0; j < 4; ++j)
        m = fmaxf(m, fmaxf(fmaxf(v[j].x, v[j].y), fmaxf(v[j].z, v[j].w)));
#pragma unroll
    for (int off = 32; off > 0; off >>= 1)
        m = fmaxf(m, __shfl_xor(m, off, 64));

    // ---- pass 2: sum exp(x-m), sum x, first-index argmax via equality
    float se = 0.0f, sx = 0.0f;
    int am = 0x7fffffff;
#pragma unroll
    for (int j = 0; j < 4; ++j) {
        float xs[4] = {v[j].x, v[j].y, v[j].z, v[j].w};
#pragma unroll
        for (int k = 0; k < 4; ++k) {
            float x = xs[k];
            int idx = j * 256 + lane * 4 + k;
            sx += x;
            se += __expf(x - m);
            if (x == m) am = min(am, idx);   // m is bit-exact one of the x's
        }
    }

    // x[target] via ONE shuffle: element idx = j*256 + lane*4 + k
    const int jt = t >> 8, lt = (t >> 2) & 63, kt = t & 3;
    float4 vj = (jt == 0) ? v[0] : (jt == 1) ? v[1] : (jt == 2) ? v[2] : v[3];
    float xc  = (kt == 0) ? vj.x : (kt == 1) ? vj.y : (kt == 2) ? vj.z : vj.w;
    float xt  = __shfl(xc, lt, 64);

#pragma unroll
    for (int off = 32; off > 0; off >>= 1) {
        se += __shfl_xor(se, off, 64);
        sx += __shfl_xor(sx, off, 64);
        am  = min(am, __shfl_xor(am, off, 64));
    }

    if (lane == 0) {
        float lse    = m + __logf(se);
        float nll    = lse - xt;                      // -logp[target]
        float smooth = lse - sx * (1.0f / (float)VV); // -mean(logp)
        ce[row]   = (t != PAD_IDX) ? (0.9f * nll + 0.1f * smooth) : 0.0f;
        pred[row] = am;
    }
}

// ---------------------------------------------------------------------------
// Kernel 2: per-batch-row stats -> SoA partials (no atomics, no contention).
// part[k][b]: 0=sum cw, 1=sum w, 2=|plen-L|, 3=bi, 4=tri, 5=correct, 6=L,
//             7=end_ok, 8=len_eq, 9=front>0
__global__ __launch_bounds__(128) void batch_kernel(
    const int* __restrict__ tgt, const float* __restrict__ ce,
    const int* __restrict__ pred, float* __restrict__ part)
{
    const int b = blockIdx.x;
    const int s = threadIdx.x;
    const int wave = s >> 6, lane = s & 63;

    __shared__ int sh_t[SS], sh_p[SS];
    __shared__ int sL[2], sPL[2], sCor[2], sFront[2];
    __shared__ float sRW[2], sRCW[2];
    __shared__ int sRBi[2], sRTri[2];

    const int   t = tgt[b * SS + s];
    const int   p = pred[b * SS + s];
    const float c = ce[b * SS + s];
    sh_t[s] = t; sh_p[s] = p;

    unsigned long long bal;
    bal = __ballot(t != PAD_IDX);               if (!lane) sL[wave]     = __popcll(bal);
    bal = __ballot(p != PAD_IDX);               if (!lane) sPL[wave]    = __popcll(bal);
    bal = __ballot(p == t && t != PAD_IDX);     if (!lane) sCor[wave]   = __popcll(bal);
    bal = __ballot(t != PAD_IDX && s < SS - 2); if (!lane) sFront[wave] = __popcll(bal);
    __syncthreads();

    const int L    = sL[0] + sL[1];
    const int plen = sPL[0] + sPL[1];

    // position weights (pos == s)
    float Lf = fmaxf((float)L, 1.0f);
    float w  = (s < L) ? 1.0f + ((float)s / Lf) * 0.5f : 1.0f;
    if (s == L - 3 && L >= 3) w = 1.8f;
    if (s == L - 2 && L >= 2) w = 2.4f;
    if (s == L - 1 && L >= 1) w = 3.0f;
    float cw = c * w;

    // bigram / trigram (exact integer terms)
    int bi = 0, tri = 0;
    if (s < SS - 1) {
        int pe = (p == sh_p[s + 1]);
        int te = (t == sh_t[s + 1]);
        int sm = (p == t);
        bi = pe + te - 2 * (pe & te & sm);
        if (s < SS - 2) {
            int pe3 = pe & (sh_p[s + 1] == sh_p[s + 2]);
            int te3 = te & (sh_t[s + 1] == sh_t[s + 2]);
            tri = pe3 + te3 - 2 * (pe3 & te3 & sm);
        }
    }

    float rw = w, rcw = cw; int rbi = bi, rtri = tri;
#pragma unroll
    for (int off = 32; off > 0; off >>= 1) {
        rw   += __shfl_xor(rw,   off, 64);
        rcw  += __shfl_xor(rcw,  off, 64);
        rbi  += __shfl_xor(rbi,  off, 64);
        rtri += __shfl_xor(rtri, off, 64);
    }
    if (!lane) { sRW[wave] = rw; sRCW[wave] = rcw; sRBi[wave] = rbi; sRTri[wave] = rtri; }
    __syncthreads();

    if (s == 0) {
        float sumw  = sRW[0] + sRW[1];
        float sumcw = sRCW[0] + sRCW[1];
        int bis   = sRBi[0]  + sRBi[1];
        int tris  = sRTri[0] + sRTri[1];
        int cor   = sCor[0]  + sCor[1];
        int front = sFront[0] + sFront[1];

        int end_idx = L - 1; if (end_idx < 0) end_idx = 0; if (end_idx > SS - 1) end_idx = SS - 1;
        int eok = (L > 0) && (sh_p[end_idx] == sh_t[end_idx]);
        int d = plen - L; if (d < 0) d = -d;

        // All magnitudes < 2^24: exact in f32.
        part[0 * BB + b] = sumcw;
        part[1 * BB + b] = sumw;
        part[2 * BB + b] = (float)d;
        part[3 * BB + b] = (float)bis;
        part[4 * BB + b] = (float)tris;
        part[5 * BB + b] = (float)cor;
        part[6 * BB + b] = (float)L;
        part[7 * BB + b] = (float)eok;
        part[8 * BB + b] = (L == plen) ? 1.0f : 0.0f;
        part[9 * BB + b] = (front > 0) ? 1.0f : 0.0f;
    }
}

// ---------------------------------------------------------------------------
// Kernel 3: reduce 512 partial records -> 4 output scalars. 1 block, 512 thr.
__global__ __launch_bounds__(512) void finalize(
    const float* __restrict__ part, float* __restrict__ out)
{
    const int t = threadIdx.x;          // 0..511, one per batch row
    const int wave = t >> 6, lane = t & 63;

    float v[NPART];
#pragma unroll
    for (int k = 0; k < NPART; ++k) v[k] = part[k * BB + t];   // coalesced

#pragma unroll
    for (int off = 32; off > 0; off >>= 1)
#pragma unroll
        for (int k = 0; k < NPART; ++k) v[k] += __shfl_xor(v[k], off, 64);

    __shared__ float sh[NPART][8];
    if (!lane)
#pragma unroll
        for (int k = 0; k < NPART; ++k) sh[k][wave] = v[k];
    __syncthreads();

    if (t == 0) {
        float s[NPART];
#pragma unroll
        for (int k = 0; k < NPART; ++k) {
            s[k] = 0.0f;
            for (int wv = 0; wv < 8; ++wv) s[k] += sh[k][wv];
        }
        float weighted = s[0] / s[1];
        float lp   = 0.1f * s[2] / (float)BB;
        float bif  = s[3] / ((float)BB * (float)(SS - 1) * (float)VV);
        float trif = s[4] / ((float)BB * (float)(SS - 2) * (float)VV);
        float cng  = bif + (s[9] > 0.0f ? trif : 0.0f);
        out[0] = weighted + lp + 0.2f * cng;                   // total_loss
        out[1] = s[6] > 0.0f ? s[5] / s[6] : 0.0f;             // char_acc
        out[2] = s[7] / (float)BB;                             // end_char_acc
        out[3] = s[8] / (float)BB;                             // length_acc
    }
}

// ---------------------------------------------------------------------------
extern "C" void kernel_launch(void* const* d_in, const int* in_sizes, int n_in,
                              void* d_out, int out_size, void* d_ws, size_t ws_size,
                              hipStream_t stream)
{
    const float* logits = (const float*)d_in[0];
    const int*   tgt    = (const int*)d_in[1];
    float* out = (float*)d_out;

    char* ws = (char*)d_ws;
    float* ce   = (float*)(ws + OFF_CE);
    int*   pred = (int*)  (ws + OFF_PRED);
    float* part = (float*)(ws + OFF_PART);

    row_kernel<<<NROWS / 4, 256, 0, stream>>>(logits, tgt, ce, pred);
    batch_kernel<<<BB, SS, 0, stream>>>(tgt, ce, pred, part);
    finalize<<<1, 512, 0, stream>>>(part, out);
}